// Round 4
// baseline (91.237 us; speedup 1.0000x reference)
//
#include <hip/hip_runtime.h>
#include <hip/hip_bf16.h>
#include <stdint.h>

// Problem: B=4, N=1024, D=512, F=16, O=64, V=64. fp32 tensors, int32 idx.
// out[b,n,f,o] = sum_d (x[b,n,d]+bias[v,d])*W[v,d,o], v=idx[b,f]
//             = (x[b] @ W[v])[n,o] + c[v][o],  c[v][o]=sum_d bias[v,d]*W[v,d,o]
// R4: gemm keeps only A in LDS (8 ds_read_b128/wave/iter, was 12); B-frags
// loaded direct from global wt (K-contiguous, L2-resident) with 1-iter
// register prefetch. prep W-part split to 512 blocks (was 64) + cv atomics.
// Measured context: dur_us includes ~70us harness reset traffic (268MB ws
// poison fill = 45us + restores); kernel-side share ~15-20us -> target ~8us.

typedef __bf16 bf16_t;
typedef __bf16 bf16x8 __attribute__((ext_vector_type(8)));
typedef float floatx4 __attribute__((ext_vector_type(4)));

__device__ __forceinline__ void async_ld16(const bf16_t* g, bf16_t* l) {
    __builtin_amdgcn_global_load_lds(
        (const __attribute__((address_space(1))) void*)g,
        (__attribute__((address_space(3))) void*)l,
        16, 0, 0);
}

// ---------------------------------------------------------------------------
// Prep: blocks [0,512): (v = bid>>3, chunk c = bid&7): transpose 64d x 64o of
//   W[v] fp32 -> bf16 wt[v][o][d], partial c[v][o] via fp32 atomics (cv
//   pre-zeroed by memsetAsync).
// blocks [512,1536): x fp32 -> bf16 xb, 2048 elements per block.
// ---------------------------------------------------------------------------
__global__ __launch_bounds__(256) void prep_kernel(
    const float* __restrict__ w,     // [64][512][64]
    const float* __restrict__ bias,  // [64][512]
    const float* __restrict__ x,     // [4096][512]
    bf16_t* __restrict__ wt,         // [64][64][512]
    float* __restrict__ cv,          // [64][64], pre-zeroed
    bf16_t* __restrict__ xb)         // [4096][512]
{
    const int t = threadIdx.x;
    if (blockIdx.x >= 512) {
        const int base = (blockIdx.x - 512) * 2048 + t * 8;
        const float4 f0 = *(const float4*)(x + base);
        const float4 f1 = *(const float4*)(x + base + 4);
        bf16x8 o;
        o[0] = (bf16_t)f0.x; o[1] = (bf16_t)f0.y;
        o[2] = (bf16_t)f0.z; o[3] = (bf16_t)f0.w;
        o[4] = (bf16_t)f1.x; o[5] = (bf16_t)f1.y;
        o[6] = (bf16_t)f1.z; o[7] = (bf16_t)f1.w;
        *(bf16x8*)(xb + base) = o;
        return;
    }

    const int v = blockIdx.x >> 3;
    const int c = blockIdx.x & 7;
    __shared__ float tile[64][68];   // [d_local][o]
    __shared__ float bch[64];
    __shared__ float red[4][64];

    // Load 64x64 fp32 chunk: 4 threads/row x 16 floats.
    const int r = t >> 2, cs = (t & 3) * 16;
    const float* src = w + (size_t)v * 32768 + (size_t)(c * 64 + r) * 64 + cs;
    *(float4*)&tile[r][cs]      = *(const float4*)(src);
    *(float4*)&tile[r][cs + 4]  = *(const float4*)(src + 4);
    *(float4*)&tile[r][cs + 8]  = *(const float4*)(src + 8);
    *(float4*)&tile[r][cs + 12] = *(const float4*)(src + 12);
    if (t < 64) bch[t] = bias[v * 512 + c * 64 + t];
    __syncthreads();

    // Transposed bf16 write: row o, 16 consecutive d.
    const int o = t >> 2, ds = (t & 3) * 16;
    bf16x8 t0, t1;
#pragma unroll
    for (int j = 0; j < 8; ++j) t0[j] = (bf16_t)tile[ds + j][o];
#pragma unroll
    for (int j = 0; j < 8; ++j) t1[j] = (bf16_t)tile[ds + 8 + j][o];
    bf16_t* dst = wt + ((size_t)v * 64 + o) * 512 + c * 64 + ds;
    *(bf16x8*)&dst[0] = t0;
    *(bf16x8*)&dst[8] = t1;

    // Partial c[v][oc] over this chunk's 64 d-rows.
    const int dq = t >> 6, oc = t & 63;
    float csum = 0.f;
#pragma unroll
    for (int j = 0; j < 16; ++j) {
        const int dl = dq * 16 + j;
        csum += bch[dl] * tile[dl][oc];
    }
    red[dq][oc] = csum;
    __syncthreads();
    if (t < 64) atomicAdd(&cv[v * 64 + t],
                          red[0][t] + red[1][t] + red[2][t] + red[3][t]);
}

// ---------------------------------------------------------------------------
// GEMM: BM=128, BN=64, BK=64, 256 threads = 4 waves (each 64x32 = 4x2 frags).
// A: LDS, XOR-swizzled (2-way banks = free), dbuf, global_load_lds DMA.
// B: DIRECT from global wt (K-contiguous; L2-resident), register dbuf with
//    1-iteration-ahead prefetch issued right after the barrier.
// Block order bid = f*32 + b*8 + mt => XCD = mt: 16 f-blocks of one (b,mt)
// share an XCD (A-tile L2 reuse); each XCD pulls W once into its L2.
// ---------------------------------------------------------------------------
__global__ __launch_bounds__(256, 2) void gemm_kernel(
    const bf16_t* __restrict__ xb,   // [4096][512]
    const bf16_t* __restrict__ wt,   // [64][64][512]
    const float*  __restrict__ cv,   // [64][64]
    const int*    __restrict__ idx,  // [4][16]
    float* __restrict__ out)         // [4096][1024], col = f*64+o
{
    const int bid = blockIdx.x;
    const int f  = bid >> 5;
    const int b  = (bid >> 3) & 3;
    const int mt = bid & 7;
    const int v  = idx[b * 16 + f];

    const int tid  = threadIdx.x;
    const int lane = tid & 63;
    const int wave = tid >> 6;
    const int wm = wave >> 1;
    const int wn = wave & 1;
    const int l15 = lane & 15;
    const int l4  = lane >> 4;

    const bf16_t* Ag = xb + (size_t)(b * 1024 + mt * 128) * 512;  // [128][512]
    const bf16_t* Bg = wt + (size_t)v * 64 * 512;                 // [64][512]

    __shared__ __align__(16) bf16_t As[2][128 * 64];  // 16KB each

    floatx4 acc[4][2] = {};

    // A staging: 1024 segs of 16B per buf; thread does s = tid + 256j.
    // row = s>>3, lds slot = s&7 holds global k8-group (s&7)^(row&7).
    int a_row[4], a_col[4];
#pragma unroll
    for (int j = 0; j < 4; ++j) {
        const int s = tid + 256 * j;
        a_row[j] = s >> 3;
        a_col[j] = ((s & 7) ^ (a_row[j] & 7)) * 8;
    }

    // B-frag global pointers: lane reads 8 consecutive k at row n.
    const bf16_t* bp[2];
#pragma unroll
    for (int ni = 0; ni < 2; ++ni)
        bp[ni] = Bg + (size_t)(wn * 32 + ni * 16 + l15) * 512 + l4 * 8;

    // Prologue: A DMA + B regs for kk=0.
#pragma unroll
    for (int j = 0; j < 4; ++j)
        async_ld16(Ag + a_row[j] * 512 + a_col[j], &As[0][(tid + 256 * j) * 8]);
    bf16x8 breg[2][2][2];  // [parity][ni][ks]
#pragma unroll
    for (int ni = 0; ni < 2; ++ni)
#pragma unroll
        for (int ks = 0; ks < 2; ++ks)
            breg[0][ni][ks] = *(const bf16x8*)(bp[ni] + ks * 32);

    for (int kk = 0; kk < 8; ++kk) {
        const int buf = kk & 1;
        __syncthreads();  // vmcnt(0) drain: As[buf] + breg[buf] ready
        if (kk < 7) {
            const int k0 = (kk + 1) * 64;
#pragma unroll
            for (int j = 0; j < 4; ++j)
                async_ld16(Ag + a_row[j] * 512 + k0 + a_col[j],
                           &As[buf ^ 1][(tid + 256 * j) * 8]);
#pragma unroll
            for (int ni = 0; ni < 2; ++ni)
#pragma unroll
                for (int ks = 0; ks < 2; ++ks)
                    breg[buf ^ 1][ni][ks] =
                        *(const bf16x8*)(bp[ni] + k0 + ks * 32);
        }
        bf16x8 a[4][2];
#pragma unroll
        for (int mi = 0; mi < 4; ++mi) {
            const int row = wm * 64 + mi * 16 + l15;
#pragma unroll
            for (int ks = 0; ks < 2; ++ks)
                a[mi][ks] = *(const bf16x8*)
                    &As[buf][row * 64 + (((ks * 4 + l4) ^ (row & 7)) * 8)];
        }
#pragma unroll
        for (int mi = 0; mi < 4; ++mi)
#pragma unroll
            for (int ni = 0; ni < 2; ++ni) {
                acc[mi][ni] = __builtin_amdgcn_mfma_f32_16x16x32_bf16(
                    a[mi][0], breg[buf][ni][0], acc[mi][ni], 0, 0, 0);
                acc[mi][ni] = __builtin_amdgcn_mfma_f32_16x16x32_bf16(
                    a[mi][1], breg[buf][ni][1], acc[mi][ni], 0, 0, 0);
            }
    }

    // Epilogue: C layout col = lane&15, row = (lane>>4)*4 + r. fp32 + c[v].
    const int colbase = wn * 32 + l15;
    const float c0 = cv[v * 64 + colbase];
    const float c1 = cv[v * 64 + colbase + 16];
    float* outp = out + (size_t)(b * 1024 + mt * 128 + wm * 64 + l4 * 4) * 1024
                      + f * 64;
#pragma unroll
    for (int mi = 0; mi < 4; ++mi) {
#pragma unroll
        for (int r = 0; r < 4; ++r) {
            float* row = outp + (size_t)(mi * 16 + r) * 1024;
            row[colbase]      = acc[mi][0][r] + c0;
            row[colbase + 16] = acc[mi][1][r] + c1;
        }
    }
}

// ---------------------------------------------------------------------------
// Fallback (ws too small): direct fp32, slow but correct.
// ---------------------------------------------------------------------------
__global__ __launch_bounds__(256) void naive_kernel(
    const float* __restrict__ x, const float* __restrict__ w,
    const float* __restrict__ bias, const int* __restrict__ idx,
    float* __restrict__ out)
{
    const int b = blockIdx.x >> 10;
    const int n = blockIdx.x & 1023;
    __shared__ float xr[512];
    for (int d = threadIdx.x; d < 512; d += 256)
        xr[d] = x[(size_t)(b * 1024 + n) * 512 + d];
    __syncthreads();
    for (int p = threadIdx.x; p < 1024; p += 256) {
        const int f = p >> 6, o = p & 63;
        const int v = idx[b * 16 + f];
        const float* wp = w + (size_t)v * 32768 + o;
        const float* bp = bias + v * 512;
        float s = 0.f;
        for (int d = 0; d < 512; ++d)
            s += (xr[d] + bp[d]) * wp[(size_t)d * 64];
        out[(size_t)(b * 1024 + n) * 1024 + p] = s;
    }
}

extern "C" void kernel_launch(void* const* d_in, const int* in_sizes, int n_in,
                              void* d_out, int out_size, void* d_ws, size_t ws_size,
                              hipStream_t stream) {
    const float* x    = (const float*)d_in[0];  // [4,1024,512]
    const int*   idx  = (const int*)d_in[1];    // [4,16]
    const float* bias = (const float*)d_in[2];  // [64,512]
    const float* w    = (const float*)d_in[3];  // [64,512,64]
    float* out = (float*)d_out;                 // [4,1024,16,64]

    const size_t cv_bytes = 64 * 64 * sizeof(float);      // 16 KB
    const size_t wt_bytes = (size_t)64 * 64 * 512 * 2;    // 4 MB
    const size_t xb_bytes = (size_t)4096 * 512 * 2;       // 4 MB
    if (ws_size >= cv_bytes + wt_bytes + xb_bytes) {
        float*  cv = (float*)d_ws;
        bf16_t* wt = (bf16_t*)((char*)d_ws + cv_bytes);
        bf16_t* xb = (bf16_t*)((char*)d_ws + cv_bytes + wt_bytes);
        hipMemsetAsync(cv, 0, cv_bytes, stream);
        prep_kernel<<<1536, 256, 0, stream>>>(w, bias, x, wt, cv, xb);
        gemm_kernel<<<512, 256, 0, stream>>>(xb, wt, cv, idx, out);
    } else {
        naive_kernel<<<4096, 256, 0, stream>>>(x, w, bias, idx, out);
    }
}

// Round 6
// 89.072 us; speedup vs baseline: 1.0243x; 1.0243x over previous
//
#include <hip/hip_runtime.h>
#include <hip/hip_bf16.h>
#include <stdint.h>

// Problem: B=4, N=1024, D=512, F=16, O=64, V=64. fp32 tensors, int32 idx.
// out[b,n,f,o] = sum_d (x[b,n,d]+bias[v,d])*W[v,d,o], v=idx[b,f]
//             = (x[b] @ W[v])[n,o] + c[v][o],  c[v][o]=sum_d bias[v,d]*W[v,d,o]
// R6 = R5 structure with __launch_bounds__(256,2) (R5's (256,3) + ~64 extra
// staging VGPRs most likely hit a register-allocation fatal error -> SIGABRT
// in the in-process compiler; 2 waves/EU caps VGPR at 256, demand ~200).
// TWO dispatches. prep (512 blocks): W fp32 -> bf16 Wt[v][o][d] + per-chunk
// c partials cvp[8][64][64] (no memset, no atomics). gemm: A staged in-kernel
// from fp32 x (float4 -> cvt -> ds_write bf16, XOR swizzle, dbuf); B register-
// prefetched from wt (K-contiguous, L2-resident); epilogue sums 8 c-partials.
// Context: dur_us includes ~55-70us harness reset floor (268MB ws poison fill
// ~45us + out poison + input restores). Kernel-side target ~9-11us.

typedef __bf16 bf16_t;
typedef __bf16 bf16x8 __attribute__((ext_vector_type(8)));
typedef float floatx4 __attribute__((ext_vector_type(4)));

// ---------------------------------------------------------------------------
// Prep: block (v = bid>>3, chunk c = bid&7): transpose 64d x 64o of W[v]
// fp32 -> bf16 wt[v][o][d]; write partial c into cvp[c][v][o] (owned slice).
// ---------------------------------------------------------------------------
__global__ __launch_bounds__(256) void prep_kernel(
    const float* __restrict__ w,     // [64][512][64]
    const float* __restrict__ bias,  // [64][512]
    bf16_t* __restrict__ wt,         // [64][64][512]
    float* __restrict__ cvp)         // [8][64][64]
{
    const int v = blockIdx.x >> 3;
    const int c = blockIdx.x & 7;
    const int t = threadIdx.x;
    __shared__ float tile[64][68];   // [d_local][o]
    __shared__ float bch[64];
    __shared__ float red[4][64];

    // Load 64x64 fp32 chunk: 4 threads/row x 16 floats, coalesced.
    const int r = t >> 2, cs = (t & 3) * 16;
    const float* src = w + (size_t)v * 32768 + (size_t)(c * 64 + r) * 64 + cs;
    *(float4*)&tile[r][cs]      = *(const float4*)(src);
    *(float4*)&tile[r][cs + 4]  = *(const float4*)(src + 4);
    *(float4*)&tile[r][cs + 8]  = *(const float4*)(src + 8);
    *(float4*)&tile[r][cs + 12] = *(const float4*)(src + 12);
    if (t < 64) bch[t] = bias[v * 512 + c * 64 + t];
    __syncthreads();

    // Transposed bf16 write: row o, 16 consecutive d.
    const int o = t >> 2, ds = (t & 3) * 16;
    bf16x8 t0, t1;
#pragma unroll
    for (int j = 0; j < 8; ++j) t0[j] = (bf16_t)tile[ds + j][o];
#pragma unroll
    for (int j = 0; j < 8; ++j) t1[j] = (bf16_t)tile[ds + 8 + j][o];
    bf16_t* dst = wt + ((size_t)v * 64 + o) * 512 + c * 64 + ds;
    *(bf16x8*)&dst[0] = t0;
    *(bf16x8*)&dst[8] = t1;

    // Partial c over this chunk's 64 d-rows -> cvp[c][v][*] (no atomics).
    const int dq = t >> 6, oc = t & 63;
    float csum = 0.f;
#pragma unroll
    for (int j = 0; j < 16; ++j) {
        const int dl = dq * 16 + j;
        csum += bch[dl] * tile[dl][oc];
    }
    red[dq][oc] = csum;
    __syncthreads();
    if (t < 64)
        cvp[c * 4096 + v * 64 + t] =
            red[0][t] + red[1][t] + red[2][t] + red[3][t];
}

// ---------------------------------------------------------------------------
// GEMM: BM=128, BN=64, BK=64, 256 threads = 4 waves (each 64x32 = 4x2 frags).
// A: fp32 x -> regs -> cvt bf16 -> LDS (XOR swizzle, conflict-free), dbuf.
// B: register dbuf direct from global wt (16B/lane, 64B-line aligned groups).
// Block order bid = f*32 + b*8 + mt => XCD = mt: f-blocks of one (b,mt) share
// an XCD (A-tile L2 reuse); W bf16 (4MB) fits each XCD L2.
// ---------------------------------------------------------------------------
__global__ __launch_bounds__(256, 2) void gemm_kernel(
    const float*  __restrict__ x,    // [4096][512] fp32
    const bf16_t* __restrict__ wt,   // [64][64][512]
    const float*  __restrict__ cvp,  // [8][64][64]
    const int*    __restrict__ idx,  // [4][16]
    float* __restrict__ out)         // [4096][1024], col = f*64+o
{
    const int bid = blockIdx.x;
    const int f  = bid >> 5;
    const int b  = (bid >> 3) & 3;
    const int mt = bid & 7;
    const int v  = idx[b * 16 + f];

    const int tid  = threadIdx.x;
    const int lane = tid & 63;
    const int wave = tid >> 6;
    const int wm = wave >> 1;
    const int wn = wave & 1;
    const int l15 = lane & 15;
    const int l4  = lane >> 4;

    const float*  Ag = x  + (size_t)(b * 1024 + mt * 128) * 512;  // [128][512]
    const bf16_t* Bg = wt + (size_t)v * 64 * 512;                 // [64][512]

    __shared__ __align__(16) bf16_t As[2][128 * 64];  // 16KB each

    floatx4 acc[4][2] = {};

    // A staging: 1024 segs of 8 k-elements; thread does s = tid + 256j.
    // row = s>>3, k8 = s&7; LDS slot (k8 ^ (row&7)) holds global k8-group.
    int a_row[4], a_k8[4], a_slot[4];
#pragma unroll
    for (int j = 0; j < 4; ++j) {
        const int s = tid + 256 * j;
        a_row[j]  = s >> 3;
        a_k8[j]   = s & 7;
        a_slot[j] = a_k8[j] ^ (a_row[j] & 7);
    }

    // B-frag global pointers: lane reads 8 consecutive k at row n.
    const bf16_t* bp[2];
#pragma unroll
    for (int ni = 0; ni < 2; ++ni)
        bp[ni] = Bg + (size_t)(wn * 32 + ni * 16 + l15) * 512 + l4 * 8;

    float4 r0[4], r1[4];          // fp32 staging regs (8 floats per seg)
    bf16x8 breg[2][2][2];         // [parity][ni][ks]

#define LOAD_A(K0)                                                        \
    {                                                                     \
        _Pragma("unroll")                                                 \
        for (int j = 0; j < 4; ++j) {                                     \
            const float* p = Ag + a_row[j] * 512 + (K0) + a_k8[j] * 8;    \
            r0[j] = *(const float4*)p;                                    \
            r1[j] = *(const float4*)(p + 4);                              \
        }                                                                 \
    }
#define WRITE_A(BUF)                                                      \
    {                                                                     \
        _Pragma("unroll")                                                 \
        for (int j = 0; j < 4; ++j) {                                     \
            bf16x8 ov;                                                    \
            ov[0] = (bf16_t)r0[j].x; ov[1] = (bf16_t)r0[j].y;             \
            ov[2] = (bf16_t)r0[j].z; ov[3] = (bf16_t)r0[j].w;             \
            ov[4] = (bf16_t)r1[j].x; ov[5] = (bf16_t)r1[j].y;             \
            ov[6] = (bf16_t)r1[j].z; ov[7] = (bf16_t)r1[j].w;             \
            *(bf16x8*)&As[BUF][a_row[j] * 64 + a_slot[j] * 8] = ov;       \
        }                                                                 \
    }

    // Prologue: stage kk=0.
    LOAD_A(0);
#pragma unroll
    for (int ni = 0; ni < 2; ++ni)
#pragma unroll
        for (int ks = 0; ks < 2; ++ks)
            breg[0][ni][ks] = *(const bf16x8*)(bp[ni] + ks * 32);
    WRITE_A(0);
    __syncthreads();

    for (int kk = 0; kk < 8; ++kk) {
        const int buf = kk & 1;
        if (kk < 7) {
            const int k0 = (kk + 1) * 64;
            LOAD_A(k0);
#pragma unroll
            for (int ni = 0; ni < 2; ++ni)
#pragma unroll
                for (int ks = 0; ks < 2; ++ks)
                    breg[buf ^ 1][ni][ks] =
                        *(const bf16x8*)(bp[ni] + k0 + ks * 32);
        }
        bf16x8 a[4][2];
#pragma unroll
        for (int mi = 0; mi < 4; ++mi) {
            const int row = wm * 64 + mi * 16 + l15;
#pragma unroll
            for (int ks = 0; ks < 2; ++ks)
                a[mi][ks] = *(const bf16x8*)
                    &As[buf][row * 64 + (((ks * 4 + l4) ^ (row & 7)) * 8)];
        }
#pragma unroll
        for (int mi = 0; mi < 4; ++mi)
#pragma unroll
            for (int ni = 0; ni < 2; ++ni) {
                acc[mi][ni] = __builtin_amdgcn_mfma_f32_16x16x32_bf16(
                    a[mi][0], breg[buf][ni][0], acc[mi][ni], 0, 0, 0);
                acc[mi][ni] = __builtin_amdgcn_mfma_f32_16x16x32_bf16(
                    a[mi][1], breg[buf][ni][1], acc[mi][ni], 0, 0, 0);
            }
        if (kk < 7) {
            WRITE_A(buf ^ 1);   // writes race nothing: buf^1's readers
            __syncthreads();    // finished before the barrier at end of kk-1
        }
    }
#undef LOAD_A
#undef WRITE_A

    // Epilogue: C layout col = lane&15, row = (lane>>4)*4 + r. Sum 8 c-parts.
    const int colbase = wn * 32 + l15;
    float c0 = 0.f, c1 = 0.f;
#pragma unroll
    for (int p = 0; p < 8; ++p) {
        c0 += cvp[p * 4096 + v * 64 + colbase];
        c1 += cvp[p * 4096 + v * 64 + colbase + 16];
    }
    float* outp = out + (size_t)(b * 1024 + mt * 128 + wm * 64 + l4 * 4) * 1024
                      + f * 64;
#pragma unroll
    for (int mi = 0; mi < 4; ++mi) {
#pragma unroll
        for (int r = 0; r < 4; ++r) {
            float* row = outp + (size_t)(mi * 16 + r) * 1024;
            row[colbase]      = acc[mi][0][r] + c0;
            row[colbase + 16] = acc[mi][1][r] + c1;
        }
    }
}

// ---------------------------------------------------------------------------
// Fallback (ws too small): direct fp32, slow but correct.
// ---------------------------------------------------------------------------
__global__ __launch_bounds__(256) void naive_kernel(
    const float* __restrict__ x, const float* __restrict__ w,
    const float* __restrict__ bias, const int* __restrict__ idx,
    float* __restrict__ out)
{
    const int b = blockIdx.x >> 10;
    const int n = blockIdx.x & 1023;
    __shared__ float xr[512];
    for (int d = threadIdx.x; d < 512; d += 256)
        xr[d] = x[(size_t)(b * 1024 + n) * 512 + d];
    __syncthreads();
    for (int p = threadIdx.x; p < 1024; p += 256) {
        const int f = p >> 6, o = p & 63;
        const int v = idx[b * 16 + f];
        const float* wp = w + (size_t)v * 32768 + o;
        const float* bp = bias + v * 512;
        float s = 0.f;
        for (int d = 0; d < 512; ++d)
            s += (xr[d] + bp[d]) * wp[(size_t)d * 64];
        out[(size_t)(b * 1024 + n) * 1024 + p] = s;
    }
}

extern "C" void kernel_launch(void* const* d_in, const int* in_sizes, int n_in,
                              void* d_out, int out_size, void* d_ws, size_t ws_size,
                              hipStream_t stream) {
    const float* x    = (const float*)d_in[0];  // [4,1024,512]
    const int*   idx  = (const int*)d_in[1];    // [4,16]
    const float* bias = (const float*)d_in[2];  // [64,512]
    const float* w    = (const float*)d_in[3];  // [64,512,64]
    float* out = (float*)d_out;                 // [4,1024,16,64]

    const size_t cvp_bytes = (size_t)8 * 64 * 64 * sizeof(float);  // 128 KB
    const size_t wt_bytes  = (size_t)64 * 64 * 512 * 2;            // 4 MB
    if (ws_size >= cvp_bytes + wt_bytes) {
        float*  cvp = (float*)d_ws;
        bf16_t* wt  = (bf16_t*)((char*)d_ws + cvp_bytes);
        prep_kernel<<<512, 256, 0, stream>>>(w, bias, wt, cvp);
        gemm_kernel<<<512, 256, 0, stream>>>(x, wt, cvp, idx, out);
    } else {
        naive_kernel<<<4096, 256, 0, stream>>>(x, w, bias, idx, out);
    }
}